// Round 6
// baseline (844.818 us; speedup 1.0000x reference)
//
#include <hip/hip_runtime.h>
#include <cmath>

#define B_   128
#define T_   64
#define IN_  2048
#define OUT_ 2048
#define IDXSTRIDE 512   // per (b,t): [0,256) half-0, [256,512) half-1 (balanced interleave)
#define HALFSTRIDE 256
#define ZOFF 131072u    // byte offset of the 64B zero row (row index 2048)

// fp64 constants == Python float64 literals
#define BETA_D   0.9
#define ACTDEC_D 0.999
#define ETA_TH_D 0.001
#define TARGET_D 0.05
#define MINW_D   (-5.0)
#define MAXW_D   (5.0)
#define MINTH_D  0.5
#define MAXTH_D  2.0

// LDS: W 2048 rows x 8 cols fp64, row-major 64B rows:
//   byte(i, col o) = (i<<6) | ((o>>1)<<4) | ((o&1)<<3)
// row 2048 (at ZOFF) is all zeros -- target of list padding entries.
// part[2][8] f32 spike-count double buffer after that.
#define PART_OFF   131136
#define SMEM_BYTES 131200

// ---- precompute: pre_rate[t][i] = mean_b x[b,t,i]  (exact: integer counts) ----
__global__ __launch_bounds__(256) void k_rate(const float* __restrict__ x,
                                              double* __restrict__ pre_rate) {
    int t = blockIdx.x;
    int i = blockIdx.y * 256 + threadIdx.x;
    const float* xp = x + (size_t)t * IN_ + i;
    float s = 0.f;
    for (int b = 0; b < B_; ++b) s += xp[(size_t)b * T_ * IN_];
    pre_rate[(size_t)t * IN_ + i] = (double)s * (1.0 / 128.0);
}

// ---- precompute combined table: prq[t][i] = (pre_tr, pre_rate) interleaved ----
__global__ __launch_bounds__(256) void k_scan(const double* __restrict__ pre_rate,
                                              double* __restrict__ prq, double decay) {
    int i = blockIdx.x * 256 + threadIdx.x;
    double tr = 0.0;
    for (int t = 0; t < T_; ++t) {
        double q = pre_rate[(size_t)t * IN_ + i];
        tr = decay * tr + q;
        *(double2*)&prq[((size_t)t * IN_ + i) * 2] = make_double2(tr, q);
    }
}

// ---- ballot-compact x into balanced half-lists, padded to multiple of 16 with ZOFF ----
__global__ __launch_bounds__(256) void k_build_idx(const float* __restrict__ x,
        unsigned* __restrict__ idx, int* __restrict__ cnt) {
    int row  = blockIdx.x * 4 + (threadIdx.x >> 6);   // b*T + t
    int lane = threadIdx.x & 63;
    const float* xr = x + (size_t)row * IN_;
    unsigned* ip = idx + (size_t)row * IDXSTRIDE;
    unsigned long long below = (1ull << lane) - 1ull;
    int c = 0;
    for (int ch = 0; ch < IN_ / 64; ++ch) {
        int i = ch * 64 + lane;
        float vv = xr[i];
        unsigned long long m = __ballot(vv != 0.0f);
        if (vv != 0.0f) {
            int pos  = c + __popcll(m & below);
            int half = pos & 1, slot = pos >> 1;
            if (slot < HALFSTRIDE) ip[half * HALFSTRIDE + slot] = (unsigned)i << 6;
        }
        c += __popcll(m);
    }
    int ce = (c + 1) >> 1; if (ce > HALFSTRIDE) ce = HALFSTRIDE;
    int co = c >> 1;       if (co > HALFSTRIDE) co = HALFSTRIDE;
    int mx = ce > co ? ce : co;
    int np = (mx + 15) & ~15;                         // multiple of 16
    if (np == 0) np = 16;
    if (np > HALFSTRIDE) np = HALFSTRIDE;
    for (int p = ce + lane; p < np; p += 64) ip[p] = ZOFF;
    for (int p = co + lane; p < np; p += 64) ip[HALFSTRIDE + p] = ZOFF;
    if (lane == 0) cnt[row] = np;
}

// gather one col-pair given byte offset r (= i<<6, bits 0..5 clear)
#define GAT(r, A0, A1) do { \
    const double2 w_ = *(const double2*)(smem + ((r) ^ cx)); \
    A0 += w_.x; A1 += w_.y; } while (0)

// ---- persistent kernel: 256 blocks x 1024 threads; block s owns cols [s*8, s*8+8) ----
// tid = b*8 + c2*2 + h : b 0..127, c2 0..3 (col-pair), h 0..1 (half-list)
__global__ __launch_bounds__(1024, 4) void k_main(
        const float* __restrict__ W, const float* __restrict__ thr,
        const float* __restrict__ Ap, const float* __restrict__ Am,
        const unsigned* __restrict__ idx, const int* __restrict__ cnt,
        const double* __restrict__ prq, float* __restrict__ out, double decay) {
    extern __shared__ char smem[];
    float* part = (float*)(smem + PART_OFF);   // [2][8]

    const int tid  = threadIdx.x;
    const int s    = blockIdx.x;
    const int lane = tid & 63;
    const int h    = tid & 1;
    const int c2   = (tid >> 1) & 3;
    const int b    = tid >> 3;
    const unsigned cx = (unsigned)c2 << 4;

    // ---- prologue: load W shard (rows s*8..s*8+8 of W = our 8 cols) into LDS fp64 ----
#pragma unroll
    for (int o = 0; o < 8; ++o) {
        const float* wr = W + (size_t)(s * 8 + o) * IN_;
        for (int i = tid; i < IN_; i += 1024) {
            *(double*)(smem + (((unsigned)i << 6) | ((unsigned)(o >> 1) << 4)
                               | ((unsigned)(o & 1) << 3))) = (double)wr[i];
        }
    }
    if (tid < 8)  ((double*)(smem + ZOFF))[tid] = 0.0;   // zero row for padding entries
    if (tid < 16) part[tid] = 0.0f;

    // per-thread persistent state for this thread's 2 columns (replicated on both h)
    double th0 = (double)thr[s * 8 + c2 * 2];
    double th1 = (double)thr[s * 8 + c2 * 2 + 1];
    double ptr0 = 0.0, ptr1 = 0.0;
    double pact0 = TARGET_D, pact1 = TARGET_D;
    double vr0 = 0.0, vr1 = 0.0;                 // membrane (h==0 lanes authoritative)
    const double apv = fabs((double)Ap[0]);
    const double amv = fabs((double)Am[0]);
    const int b2 = (b << 1) | h;                 // 0..255 (P3 row class)
    __syncthreads();

    // preload step-0 list head (count + first 16 entries)
    const unsigned* ip0 = idx + (size_t)(b * T_) * IDXSTRIDE + h * HALFSTRIDE;
    int   n   = cnt[b * T_];
    uint4 qa0 = *(const uint4*)(ip0);
    uint4 qa1 = *(const uint4*)(ip0 + 4);
    uint4 qb0 = *(const uint4*)(ip0 + 8);
    uint4 qb1 = *(const uint4*)(ip0 + 12);

    for (int t = 0; t < T_; ++t) {
        const int pb = t & 1;
        const int row = b * T_ + t;
        const unsigned* ip = idx + (size_t)row * IDXSTRIDE + h * HALFSTRIDE;

        // ---- P1: sparse fp64 gather; n is a multiple of 16, >= 16; no tail ----
        double a0 = 0.0, a1 = 0.0, e0 = 0.0, e1 = 0.0;
        int j = 0;
        for (;;) {
            uint4 ca0 = qa0, ca1 = qa1, cb0 = qb0, cb1 = qb1;
            int jn = j + 16;
            if (jn < n) {                         // prefetch next group of 16
                qa0 = *(const uint4*)(ip + jn);
                qa1 = *(const uint4*)(ip + jn + 4);
                qb0 = *(const uint4*)(ip + jn + 8);
                qb1 = *(const uint4*)(ip + jn + 12);
            }
            GAT(ca0.x, a0, a1); GAT(ca0.y, e0, e1);
            GAT(ca0.z, a0, a1); GAT(ca0.w, e0, e1);
            GAT(ca1.x, a0, a1); GAT(ca1.y, e0, e1);
            GAT(ca1.z, a0, a1); GAT(ca1.w, e0, e1);
            GAT(cb0.x, a0, a1); GAT(cb0.y, e0, e1);
            GAT(cb0.z, a0, a1); GAT(cb0.w, e0, e1);
            GAT(cb1.x, a0, a1); GAT(cb1.y, e0, e1);
            GAT(cb1.z, a0, a1); GAT(cb1.w, e0, e1);
            j = jn;
            if (j >= n) break;
        }
        a0 += e0; a1 += e1;
        // combine the two halves across the h-pair (both lanes end up identical)
        a0 += __shfl_xor(a0, 1);
        a1 += __shfl_xor(a1, 1);

        // prefetch next step's list head NOW (hides under P2/P3 + barriers)
        {
            int rown = row + ((t + 1 < T_) ? 1 : 0);
            const unsigned* ipn = idx + (size_t)rown * IDXSTRIDE + h * HALFSTRIDE;
            n   = cnt[rown];
            qa0 = *(const uint4*)(ipn);
            qa1 = *(const uint4*)(ipn + 4);
            qb0 = *(const uint4*)(ipn + 8);
            qb1 = *(const uint4*)(ipn + 12);
        }

        // preload P3 table entries (pre_tr, pre_rate) for this t into registers
        double2 pq[8];
        {
            const double* pt = prq + ((size_t)t * IN_) * 2;
#pragma unroll
            for (int k = 0; k < 8; ++k)
                pq[k] = *(const double2*)&pt[(k * 256 + b2) * 2];
        }

        float s0 = 0.f, s1 = 0.f;
        if (h == 0) {
            double v0 = BETA_D * vr0 + a0;
            double v1 = BETA_D * vr1 + a1;
            s0 = (v0 >= th0) ? 1.0f : 0.0f;
            s1 = (v1 >= th1) ? 1.0f : 0.0f;
            *(float2*)(out + (size_t)row * OUT_ + s * 8 + c2 * 2) = make_float2(s0, s1);
            vr0 = (s0 != 0.0f) ? 0.0 : v0;
            vr1 = (s1 != 0.0f) ? 0.0 : v1;
        }

        if (t + 1 < T_) {
            // spike-count tree over the 8 b's in this wave (lane bits 3..5)
            float r0 = s0, r1 = s1;
            r0 += __shfl_xor(r0, 8);  r1 += __shfl_xor(r1, 8);
            r0 += __shfl_xor(r0, 16); r1 += __shfl_xor(r1, 16);
            r0 += __shfl_xor(r0, 32); r1 += __shfl_xor(r1, 32);
            if (lane < 8 && (lane & 1) == 0) {       // 4 lanes: one per c2
                atomicAdd(&part[pb * 8 + c2 * 2], r0);
                atomicAdd(&part[pb * 8 + c2 * 2 + 1], r1);
            }
            if (tid < 8) part[(pb ^ 1) * 8 + tid] = 0.0f;   // prep buffer for t+1
            __syncthreads();

            // ---- P2 (redundant per-thread): scalar chain for this thread's 2 cols ----
            float cf0 = part[pb * 8 + c2 * 2];
            float cf1 = part[pb * 8 + c2 * 2 + 1];
            double prate0 = (double)cf0 * (1.0 / 128.0);
            double prate1 = (double)cf1 * (1.0 / 128.0);
            ptr0 = decay * ptr0 + prate0;
            ptr1 = decay * ptr1 + prate1;
            pact0 = ACTDEC_D * pact0 + (1.0 - ACTDEC_D) * prate0;
            pact1 = ACTDEC_D * pact1 + (1.0 - ACTDEC_D) * prate1;
            double r_ = pact0 / TARGET_D;
            r_ = r_ < 0.5 ? 0.5 : (r_ > 2.0 ? 2.0 : r_);
            double meta0 = 1.0 / r_;
            r_ = pact1 / TARGET_D;
            r_ = r_ < 0.5 ? 0.5 : (r_ > 2.0 ? 2.0 : r_);
            double meta1 = 1.0 / r_;
            double ca0 = apv * prate0 * meta0;
            double ca1 = apv * prate1 * meta1;
            double cb0 = amv * ptr0 * meta0;
            double cb1 = amv * ptr1 * meta1;
            double thv = th0 * (1.0 + ETA_TH_D * (prate0 - TARGET_D));
            th0 = thv < MINTH_D ? MINTH_D : (thv > MAXTH_D ? MAXTH_D : thv);
            thv = th1 * (1.0 + ETA_TH_D * (prate1 - TARGET_D));
            th1 = thv < MINTH_D ? MINTH_D : (thv > MAXTH_D ? MAXTH_D : thv);

            // ---- P3: in-LDS soft-bounded STDP update of W shard (tables in regs) ----
#pragma unroll
            for (int k = 0; k < 8; ++k) {
                int i = k * 256 + b2;
                double p = pq[k].x, q = pq[k].y;
                double2* wp = (double2*)(smem + (((unsigned)i << 6) | cx));
                double2 w2 = *wp;
                double dw0 = ca0 * p - cb0 * q;
                double dw1 = ca1 * p - cb1 * q;
                double dwb0 = dw0 > 0.0 ? (dw0 * (MAXW_D - w2.x)) / 10.0
                                        : (dw0 * (w2.x - MINW_D)) / 10.0;
                double dwb1 = dw1 > 0.0 ? (dw1 * (MAXW_D - w2.y)) / 10.0
                                        : (dw1 * (w2.y - MINW_D)) / 10.0;
                double nw0 = w2.x + dwb0;
                nw0 = nw0 < MINW_D ? MINW_D : (nw0 > MAXW_D ? MAXW_D : nw0);
                double nw1 = w2.y + dwb1;
                nw1 = nw1 < MINW_D ? MINW_D : (nw1 > MAXW_D ? MAXW_D : nw1);
                *wp = make_double2(nw0, nw1);
            }
            __syncthreads();
        }
    }
}

extern "C" void kernel_launch(void* const* d_in, const int* in_sizes, int n_in,
                              void* d_out, int out_size, void* d_ws, size_t ws_size,
                              hipStream_t stream) {
    const float* x   = (const float*)d_in[0];
    const float* W   = (const float*)d_in[1];
    const float* thr = (const float*)d_in[2];
    const float* Ap  = (const float*)d_in[3];
    const float* Am  = (const float*)d_in[4];
    float* out = (float*)d_out;
    char* ws = (char*)d_ws;

    // workspace: pre_rate 1MB | prq 2MB | idx 16.8MB | cnt 32KB
    double* pre_rate = (double*)(ws);
    double* prq      = (double*)(ws + 1048576);
    unsigned* idx    = (unsigned*)(ws + 1048576 + 2097152);
    int* cnt         = (int*)(ws + 1048576 + 2097152 + 16777216);

    double decay = std::exp(-1.0 / 20.0);

    (void)hipFuncSetAttribute((const void*)k_main,
                              hipFuncAttributeMaxDynamicSharedMemorySize, SMEM_BYTES);

    k_rate<<<dim3(T_, IN_ / 256), 256, 0, stream>>>(x, pre_rate);
    k_scan<<<IN_ / 256, 256, 0, stream>>>(pre_rate, prq, decay);
    k_build_idx<<<(B_ * T_) / 4, 256, 0, stream>>>(x, idx, cnt);
    k_main<<<256, 1024, SMEM_BYTES, stream>>>(W, thr, Ap, Am, idx, cnt,
                                              prq, out, decay);
}

// Round 7
// 807.466 us; speedup vs baseline: 1.0463x; 1.0463x over previous
//
#include <hip/hip_runtime.h>
#include <cmath>

#define B_   128
#define T_   64
#define IN_  2048
#define OUT_ 2048
#define IDXSTRIDE 512   // per (b,t): [0,256) even-i offsets, [256,512) odd-i offsets
#define HALFSTRIDE 256
#define ZOFF  131072u   // byte offset of zero row 2048 (even-parity pad target)
#define ZOFF1 131136u   // byte offset of zero row 2049 (odd-parity pad target)

// fp64 constants == Python float64 literals
#define BETA_D   0.9
#define ACTDEC_D 0.999
#define ETA_TH_D 0.001
#define TARGET_D 0.05
#define MINW_D   (-5.0)
#define MAXW_D   (5.0)
#define MINTH_D  0.5
#define MAXTH_D  2.0

// LDS: W 2048 rows x 8 cols fp64, row-major 64B rows:
//   byte(i, col o) = (i<<6) | ((o>>1)<<4) | ((o&1)<<3)
// rows 2048/2049 are zero rows (pad targets, parity-matched).
// part[2][8] f32 spike-count double buffer after that.
#define PART_OFF   131200
#define SMEM_BYTES 131264

// ---- precompute: pre_rate[t][i] = mean_b x[b,t,i]  (exact: integer counts) ----
__global__ __launch_bounds__(256) void k_rate(const float* __restrict__ x,
                                              double* __restrict__ pre_rate) {
    int t = blockIdx.x;
    int i = blockIdx.y * 256 + threadIdx.x;
    const float* xp = x + (size_t)t * IN_ + i;
    float s = 0.f;
    for (int b = 0; b < B_; ++b) s += xp[(size_t)b * T_ * IN_];
    pre_rate[(size_t)t * IN_ + i] = (double)s * (1.0 / 128.0);
}

// ---- precompute combined table: prq[t][i] = (pre_tr, pre_rate) interleaved ----
__global__ __launch_bounds__(256) void k_scan(const double* __restrict__ pre_rate,
                                              double* __restrict__ prq, double decay) {
    int i = blockIdx.x * 256 + threadIdx.x;
    double tr = 0.0;
    for (int t = 0; t < T_; ++t) {
        double q = pre_rate[(size_t)t * IN_ + i];
        tr = decay * tr + q;
        *(double2*)&prq[((size_t)t * IN_ + i) * 2] = make_double2(tr, q);
    }
}

// ---- ballot-compact x into PARITY-SPLIT half-lists, 8-padded with parity zero rows ----
__global__ __launch_bounds__(256) void k_build_idx(const float* __restrict__ x,
        unsigned* __restrict__ idx, int* __restrict__ cnt) {
    int row  = blockIdx.x * 4 + (threadIdx.x >> 6);   // b*T + t
    int lane = threadIdx.x & 63;
    const float* xr = x + (size_t)row * IN_;
    unsigned* ip = idx + (size_t)row * IDXSTRIDE;
    const unsigned long long EVEN = 0x5555555555555555ull;
    unsigned long long below = (1ull << lane) - 1ull;
    int ce = 0, co = 0;
    for (int ch = 0; ch < IN_ / 64; ++ch) {
        int i = ch * 64 + lane;
        float vv = xr[i];
        unsigned long long m = __ballot(vv != 0.0f);
        unsigned long long me = m & EVEN, mo = m & ~EVEN;
        if (vv != 0.0f) {
            if ((lane & 1) == 0) {
                int pos = ce + __popcll(me & below);
                if (pos < HALFSTRIDE) ip[pos] = (unsigned)i << 6;
            } else {
                int pos = co + __popcll(mo & below);
                if (pos < HALFSTRIDE) ip[HALFSTRIDE + pos] = (unsigned)i << 6;
            }
        }
        ce += __popcll(me);
        co += __popcll(mo);
    }
    if (ce > HALFSTRIDE) ce = HALFSTRIDE;
    if (co > HALFSTRIDE) co = HALFSTRIDE;
    int mx = ce > co ? ce : co;
    int np = (mx + 7) & ~7;                           // multiple of 8
    if (np == 0) np = 8;
    if (np > HALFSTRIDE) np = HALFSTRIDE;
    for (int p = ce + lane; p < np; p += 64) ip[p] = ZOFF;                 // even pad
    for (int p = co + lane; p < np; p += 64) ip[HALFSTRIDE + p] = ZOFF1;   // odd pad
    if (lane == 0) cnt[row] = np;
}

// gather one col-pair given byte offset r (= i<<6, bits 0..5 clear)
#define GAT(r, A0, A1) do { \
    const double2 w_ = *(const double2*)(smem + ((r) ^ cx)); \
    A0 += w_.x; A1 += w_.y; } while (0)

// ---- persistent kernel: 256 blocks x 1024 threads; block s owns cols [s*8, s*8+8) ----
// tid = b*8 + c2*2 + h : b 0..127, c2 0..3 (col-pair), h 0..1 (parity half-list)
__global__ __launch_bounds__(1024, 4) void k_main(
        const float* __restrict__ W, const float* __restrict__ thr,
        const float* __restrict__ Ap, const float* __restrict__ Am,
        const unsigned* __restrict__ idx, const int* __restrict__ cnt,
        const double* __restrict__ prq, float* __restrict__ out, double decay) {
    extern __shared__ char smem[];
    float* part = (float*)(smem + PART_OFF);   // [2][8]

    const int tid  = threadIdx.x;
    const int s    = blockIdx.x;
    const int lane = tid & 63;
    const int h    = tid & 1;
    const int c2   = (tid >> 1) & 3;
    const int b    = tid >> 3;
    const unsigned cx = (unsigned)c2 << 4;

    // ---- prologue: load W shard (rows s*8..s*8+8 of W = our 8 cols) into LDS fp64 ----
#pragma unroll
    for (int o = 0; o < 8; ++o) {
        const float* wr = W + (size_t)(s * 8 + o) * IN_;
        for (int i = tid; i < IN_; i += 1024) {
            *(double*)(smem + (((unsigned)i << 6) | ((unsigned)(o >> 1) << 4)
                               | ((unsigned)(o & 1) << 3))) = (double)wr[i];
        }
    }
    if (tid < 16) ((double*)(smem + ZOFF))[tid] = 0.0;   // zero rows 2048 & 2049
    if (tid < 16) part[tid] = 0.0f;

    // per-thread persistent state for this thread's 2 columns (replicated on both h)
    double th0 = (double)thr[s * 8 + c2 * 2];
    double th1 = (double)thr[s * 8 + c2 * 2 + 1];
    double ptr0 = 0.0, ptr1 = 0.0;
    double pact0 = TARGET_D, pact1 = TARGET_D;
    double vr0 = 0.0, vr1 = 0.0;                 // membrane (h==0 lanes authoritative)
    const double apv = fabs((double)Ap[0]);
    const double amv = fabs((double)Am[0]);
    const int b2 = (b << 1) | h;                 // 0..255 (P3 row class)
    __syncthreads();

    // preload step-0 list head (count + first 8 entries)
    const unsigned* ip0 = idx + (size_t)(b * T_) * IDXSTRIDE + h * HALFSTRIDE;
    int   n  = cnt[b * T_];
    uint4 q0 = *(const uint4*)(ip0);
    uint4 q1 = *(const uint4*)(ip0 + 4);

    for (int t = 0; t < T_; ++t) {
        const int pb = t & 1;
        const int row = b * T_ + t;
        const unsigned* ip = idx + (size_t)row * IDXSTRIDE + h * HALFSTRIDE;

        // ---- P1: sparse fp64 gather; n is a multiple of 8, >= 8; no tail ----
        double a0 = 0.0, a1 = 0.0, e0 = 0.0, e1 = 0.0;
        int j = 0;
        for (;;) {
            uint4 qa = q0, qb = q1;
            int jn = j + 8;
            if (jn < n) {                         // prefetch next group of 8
                q0 = *(const uint4*)(ip + jn);
                q1 = *(const uint4*)(ip + jn + 4);
            }
            GAT(qa.x, a0, a1); GAT(qa.y, e0, e1);
            GAT(qa.z, a0, a1); GAT(qa.w, e0, e1);
            GAT(qb.x, a0, a1); GAT(qb.y, e0, e1);
            GAT(qb.z, a0, a1); GAT(qb.w, e0, e1);
            j = jn;
            if (j >= n) break;
        }
        a0 += e0; a1 += e1;
        // combine even/odd halves across the h-pair (both lanes end up identical)
        a0 += __shfl_xor(a0, 1);
        a1 += __shfl_xor(a1, 1);

        // prefetch next step's list head NOW (hides under P2/P3 + barriers)
        {
            int rown = row + ((t + 1 < T_) ? 1 : 0);
            const unsigned* ipn = idx + (size_t)rown * IDXSTRIDE + h * HALFSTRIDE;
            n  = cnt[rown];
            q0 = *(const uint4*)(ipn);
            q1 = *(const uint4*)(ipn + 4);
        }

        // preload P3 table entries (pre_tr, pre_rate) for this t into registers
        double2 pq[8];
        {
            const double* pt = prq + ((size_t)t * IN_) * 2;
#pragma unroll
            for (int k = 0; k < 8; ++k)
                pq[k] = *(const double2*)&pt[(k * 256 + b2) * 2];
        }

        float s0 = 0.f, s1 = 0.f;
        if (h == 0) {
            double v0 = BETA_D * vr0 + a0;
            double v1 = BETA_D * vr1 + a1;
            s0 = (v0 >= th0) ? 1.0f : 0.0f;
            s1 = (v1 >= th1) ? 1.0f : 0.0f;
            *(float2*)(out + (size_t)row * OUT_ + s * 8 + c2 * 2) = make_float2(s0, s1);
            vr0 = (s0 != 0.0f) ? 0.0 : v0;
            vr1 = (s1 != 0.0f) ? 0.0 : v1;
        }

        if (t + 1 < T_) {
            // spike-count tree over the 8 b's in this wave (lane bits 3..5)
            float r0 = s0, r1 = s1;
            r0 += __shfl_xor(r0, 8);  r1 += __shfl_xor(r1, 8);
            r0 += __shfl_xor(r0, 16); r1 += __shfl_xor(r1, 16);
            r0 += __shfl_xor(r0, 32); r1 += __shfl_xor(r1, 32);
            if (lane < 8 && (lane & 1) == 0) {       // 4 lanes: one per c2
                atomicAdd(&part[pb * 8 + c2 * 2], r0);
                atomicAdd(&part[pb * 8 + c2 * 2 + 1], r1);
            }
            if (tid < 8) part[(pb ^ 1) * 8 + tid] = 0.0f;   // prep buffer for t+1
            __syncthreads();

            // ---- P2 (redundant per-thread): scalar chain for this thread's 2 cols ----
            float cf0 = part[pb * 8 + c2 * 2];
            float cf1 = part[pb * 8 + c2 * 2 + 1];
            double prate0 = (double)cf0 * (1.0 / 128.0);
            double prate1 = (double)cf1 * (1.0 / 128.0);
            ptr0 = decay * ptr0 + prate0;
            ptr1 = decay * ptr1 + prate1;
            pact0 = ACTDEC_D * pact0 + (1.0 - ACTDEC_D) * prate0;
            pact1 = ACTDEC_D * pact1 + (1.0 - ACTDEC_D) * prate1;
            double r_ = pact0 / TARGET_D;
            r_ = r_ < 0.5 ? 0.5 : (r_ > 2.0 ? 2.0 : r_);
            double meta0 = 1.0 / r_;
            r_ = pact1 / TARGET_D;
            r_ = r_ < 0.5 ? 0.5 : (r_ > 2.0 ? 2.0 : r_);
            double meta1 = 1.0 / r_;
            double ca0 = apv * prate0 * meta0;
            double ca1 = apv * prate1 * meta1;
            double cb0 = amv * ptr0 * meta0;
            double cb1 = amv * ptr1 * meta1;
            double thv = th0 * (1.0 + ETA_TH_D * (prate0 - TARGET_D));
            th0 = thv < MINTH_D ? MINTH_D : (thv > MAXTH_D ? MAXTH_D : thv);
            thv = th1 * (1.0 + ETA_TH_D * (prate1 - TARGET_D));
            th1 = thv < MINTH_D ? MINTH_D : (thv > MAXTH_D ? MAXTH_D : thv);

            // ---- P3: in-LDS soft-bounded STDP update of W shard (tables in regs) ----
#pragma unroll
            for (int k = 0; k < 8; ++k) {
                int i = k * 256 + b2;
                double p = pq[k].x, q = pq[k].y;
                double2* wp = (double2*)(smem + (((unsigned)i << 6) | cx));
                double2 w2 = *wp;
                double dw0 = ca0 * p - cb0 * q;
                double dw1 = ca1 * p - cb1 * q;
                double dwb0 = dw0 > 0.0 ? (dw0 * (MAXW_D - w2.x)) / 10.0
                                        : (dw0 * (w2.x - MINW_D)) / 10.0;
                double dwb1 = dw1 > 0.0 ? (dw1 * (MAXW_D - w2.y)) / 10.0
                                        : (dw1 * (w2.y - MINW_D)) / 10.0;
                double nw0 = w2.x + dwb0;
                nw0 = nw0 < MINW_D ? MINW_D : (nw0 > MAXW_D ? MAXW_D : nw0);
                double nw1 = w2.y + dwb1;
                nw1 = nw1 < MINW_D ? MINW_D : (nw1 > MAXW_D ? MAXW_D : nw1);
                *wp = make_double2(nw0, nw1);
            }
            __syncthreads();
        }
    }
}

extern "C" void kernel_launch(void* const* d_in, const int* in_sizes, int n_in,
                              void* d_out, int out_size, void* d_ws, size_t ws_size,
                              hipStream_t stream) {
    const float* x   = (const float*)d_in[0];
    const float* W   = (const float*)d_in[1];
    const float* thr = (const float*)d_in[2];
    const float* Ap  = (const float*)d_in[3];
    const float* Am  = (const float*)d_in[4];
    float* out = (float*)d_out;
    char* ws = (char*)d_ws;

    // workspace: pre_rate 1MB | prq 2MB | idx 16.8MB | cnt 32KB
    double* pre_rate = (double*)(ws);
    double* prq      = (double*)(ws + 1048576);
    unsigned* idx    = (unsigned*)(ws + 1048576 + 2097152);
    int* cnt         = (int*)(ws + 1048576 + 2097152 + 16777216);

    double decay = std::exp(-1.0 / 20.0);

    (void)hipFuncSetAttribute((const void*)k_main,
                              hipFuncAttributeMaxDynamicSharedMemorySize, SMEM_BYTES);

    k_rate<<<dim3(T_, IN_ / 256), 256, 0, stream>>>(x, pre_rate);
    k_scan<<<IN_ / 256, 256, 0, stream>>>(pre_rate, prq, decay);
    k_build_idx<<<(B_ * T_) / 4, 256, 0, stream>>>(x, idx, cnt);
    k_main<<<256, 1024, SMEM_BYTES, stream>>>(W, thr, Ap, Am, idx, cnt,
                                              prq, out, decay);
}